// Round 1
// baseline (584.830 us; speedup 1.0000x reference)
//
#include <hip/hip_runtime.h>
#include <cstdint>
#include <cstddef>

// Problem constants
#define TT   2048
#define BB   64
#define KK   512
#define OO   512
#define NCH  64      // time chunks
#define TC   32      // t-steps per chunk (1 t-step per iteration)

typedef __attribute__((ext_vector_type(8))) short short8;
typedef __attribute__((ext_vector_type(4))) float f32x4;

__device__ __forceinline__ unsigned short f2bf(float f) {
  unsigned int u = __float_as_uint(f);
  unsigned int rounding = 0x7FFFu + ((u >> 16) & 1u);
  return (unsigned short)((u + rounding) >> 16);
}

__device__ __forceinline__ float sigmoid_f(float z) {
  return 1.0f / (1.0f + __expf(-z));
}

__device__ __forceinline__ float tanh_f(float z) {
  z = fminf(15.0f, fmaxf(-15.0f, z));
  float e = __expf(-2.0f * z);
  return (1.0f - e) / (1.0f + e);
}

// ---------------- kernel 1: transpose+convert weights ----------------
// Gt[o][k] = bf16(g[k][o]); Ht likewise. grid (16,16,2), block (32,8)
__global__ void prep_weights_k(const float* __restrict__ g,
                               const float* __restrict__ h,
                               unsigned short* __restrict__ Gt,
                               unsigned short* __restrict__ Ht) {
  __shared__ float tile[32][33];
  const float* src = (blockIdx.z == 0) ? g : h;
  unsigned short* dst = (blockIdx.z == 0) ? Gt : Ht;
  int ox = blockIdx.x * 32;   // o base
  int ky = blockIdx.y * 32;   // k base
  int tx = threadIdx.x, ty = threadIdx.y;
  #pragma unroll
  for (int r = ty; r < 32; r += 8)
    tile[r][tx] = src[(ky + r) * OO + ox + tx];
  __syncthreads();
  #pragma unroll
  for (int r = ty; r < 32; r += 8)
    dst[(size_t)(ox + r) * KK + ky + tx] = f2bf(tile[tx][r]);
}

// ---------------- kernel 2: register-B fused convert+GEMM+gates+scan ------
// 256 blocks (1/CU), 512 threads (8 waves = 2/SIMD). Weights live in VGPRs:
// wave w owns o-cols [ot*128 + 16w, +16) of BOTH G and H (128 VGPRs).
// x is read DIRECTLY as fp32 and converted to bf16 in-register during
// staging (T14 issue-early/write-late: loads issued before the MFMA half,
// vmcnt-drained at the convert point ~2.5K cycles later). This removes the
// former standalone convert kernel and its 384 MB HBM round trip.
// LDS layout identical to the DMA version: LDS[r][slot s] holds global
// 16B-chunk (s&~7)|((s&7)^(r&7)) so the read-side XOR swizzle is unchanged.
__global__ __launch_bounds__(512, 2) void rnn_fused3_k(
    const float* __restrict__ x,             // [T*B][K] fp32
    const unsigned short* __restrict__ Gt,   // [OO][KK] bf16
    const unsigned short* __restrict__ Ht,   // [OO][KK] bf16
    const float* __restrict__ gb, const float* __restrict__ hb,
    const float* __restrict__ r,  const float* __restrict__ rb,
    float* __restrict__ chunkA, float* __restrict__ chunkB) {
  extern __shared__ __align__(16) unsigned short smem[];  // 2 x [64][512]

  const int tid  = threadIdx.x;
  const int wave = tid >> 6;   // 0..7
  const int lane = tid & 63;
  const int quad = lane >> 4;
  const int lcol = lane & 15;

  // bi = ot*64 + c: the 4 o-tiles of chunk c share bi%8 -> same XCD, so the
  // fp32 x-tile is fetched from HBM once and L2-served to the other 3.
  const int bi = blockIdx.x;
  const int ot = bi >> 6;      // 0..3
  const int c  = bi & 63;      // 0..63
  const int o  = ot * 128 + wave * 16 + lcol;   // this thread's output column

  const float gbv = gb[o], hbv = hb[o];
  const float rv  = r[o],  rbv = rb[o];

  // ---- weights into registers: 16 cols x K512 x {G,H} = 128 VGPRs ----
  short8 Bg[8][2], Bh[8][2];
  {
    const unsigned short* gp = Gt + (size_t)o * KK + quad * 8;
    const unsigned short* hp = Ht + (size_t)o * KK + quad * 8;
    #pragma unroll
    for (int kc = 0; kc < 8; ++kc)
      #pragma unroll
      for (int ks = 0; ks < 2; ++ks) {
        Bg[kc][ks] = *(const short8*)(gp + kc * 64 + ks * 32);
        Bh[kc][ks] = *(const short8*)(hp + kc * 64 + ks * 32);
      }
  }

  // Register staging, 4 rows per batch (32 VGPRs in flight).
  // Row rr of this wave's 8-row slab; lane fetches swizzled global chunk
  // gch = (lane&~7)|((lane&7)^rr)  (32B = 2 x float4), so the linear LDS
  // write at slot=lane reproduces the old DMA layout exactly.
  auto issue4 = [&](int trow, int half, f32x4 (&v)[4][2]) {
    const float* src = x + ((size_t)trow * BB + wave * 8) * KK;
    #pragma unroll
    for (int j = 0; j < 4; ++j) {
      int rr = half * 4 + j;
      int gch = (lane & ~7) | ((lane & 7) ^ rr);
      const float* p0 = src + (size_t)rr * KK + (size_t)gch * 8;
      v[j][0] = *(const f32x4*)(p0);
      v[j][1] = *(const f32x4*)(p0 + 4);
    }
  };
  auto write4 = [&](int buf, int half, f32x4 (&v)[4][2]) {
    unsigned short* dst = smem + buf * 32768 + wave * 8 * 512;
    #pragma unroll
    for (int j = 0; j < 4; ++j) {
      int rr = half * 4 + j;
      short8 w;
      #pragma unroll
      for (int e = 0; e < 4; ++e) w[e]     = (short)f2bf(v[j][0][e]);
      #pragma unroll
      for (int e = 0; e < 4; ++e) w[4 + e] = (short)f2bf(v[j][1][e]);
      *(short8*)(dst + rr * 512 + lane * 8) = w;
    }
  };

  // prologue: stage tile for t = c*TC into buffer 0
  {
    f32x4 s0[4][2], s1[4][2];
    issue4(c * TC, 0, s0);
    issue4(c * TC, 1, s1);
    write4(0, 0, s0);
    write4(0, 1, s1);
  }

  // chunk-scan state per (b,o) slot: y_out = SB + SA*y_in
  float SA[16], SB[16];
  #pragma unroll
  for (int s = 0; s < 16; s++) { SA[s] = 1.0f; SB[s] = 0.0f; }

  f32x4 accG[4], accH[4];
  #pragma unroll
  for (int m = 0; m < 4; m++) {
    f32x4 z = {0.0f, 0.0f, 0.0f, 0.0f};
    accG[m] = z; accH[m] = z;
  }

  __syncthreads();   // prologue LDS writes visible

  int p = 0;
  for (int it = 0; it < TC; ++it) {
    const bool pref = (it + 1 < TC);
    f32x4 st[4][2];

    if (pref) issue4(c * TC + it + 1, 0, st);   // batch0 loads in flight

    const unsigned short* A0 = smem + p * 32768;
    // ---- first compute half: kc 0..3 ----
    #pragma unroll
    for (int kc = 0; kc < 4; ++kc)
      #pragma unroll
      for (int ks = 0; ks < 2; ++ks)
        #pragma unroll
        for (int mt = 0; mt < 4; ++mt) {
          int arow = mt * 16 + lcol;
          int slot = kc * 8 + ((ks * 4 + quad) ^ (arow & 7));
          short8 a = *(const short8*)(A0 + arow * 512 + slot * 8);
          accG[mt] = __builtin_amdgcn_mfma_f32_16x16x32_bf16(
              a, Bg[kc][ks], accG[mt], 0, 0, 0);
          accH[mt] = __builtin_amdgcn_mfma_f32_16x16x32_bf16(
              a, Bh[kc][ks], accH[mt], 0, 0, 0);
        }

    if (pref) {
      write4(p ^ 1, 0, st);                      // drain batch0, convert, write
      issue4(c * TC + it + 1, 1, st);            // batch1 loads in flight
    }

    // ---- second compute half: kc 4..7 ----
    #pragma unroll
    for (int kc = 4; kc < 8; ++kc)
      #pragma unroll
      for (int ks = 0; ks < 2; ++ks)
        #pragma unroll
        for (int mt = 0; mt < 4; ++mt) {
          int arow = mt * 16 + lcol;
          int slot = kc * 8 + ((ks * 4 + quad) ^ (arow & 7));
          short8 a = *(const short8*)(A0 + arow * 512 + slot * 8);
          accG[mt] = __builtin_amdgcn_mfma_f32_16x16x32_bf16(
              a, Bg[kc][ks], accG[mt], 0, 0, 0);
          accH[mt] = __builtin_amdgcn_mfma_f32_16x16x32_bf16(
              a, Bh[kc][ks], accH[mt], 0, 0, 0);
        }

    // epilogue: one t-step of the recurrence, folded into (SA,SB)
    const int t = c * TC + it;
    const float rt = 2.0f * sigmoid_f(((float)t * (1.0f / TT)) * rv + rbv);
    #pragma unroll
    for (int mt = 0; mt < 4; ++mt)
      #pragma unroll
      for (int reg = 0; reg < 4; ++reg) {
        float G = sigmoid_f(accG[mt][reg] + gbv) * rt;
        float H = tanh_f  (accH[mt][reg] + hbv) * rt;
        int s = mt * 4 + reg;
        SB[s] = fmaf(G, SB[s], H);
        SA[s] *= G;
        accG[mt][reg] = 0.0f;
        accH[mt][reg] = 0.0f;
      }

    if (pref) write4(p ^ 1, 1, st);              // drain batch1, convert, write

    __syncthreads();   // buffer p released; p^1 fully written
    p ^= 1;
  }

  // write chunk composition: layout [c][b][o]
  #pragma unroll
  for (int mt = 0; mt < 4; ++mt)
    #pragma unroll
    for (int reg = 0; reg < 4; ++reg) {
      int s = mt * 4 + reg;
      int b = mt * 16 + quad * 4 + reg;
      size_t idx = ((size_t)c * BB + b) * OO + o;
      chunkA[idx] = SA[s];
      chunkB[idx] = SB[s];
    }
}

// ---------------- kernel 3: fold chunks ----------------
__global__ void combine_k(const float* __restrict__ cA,
                          const float* __restrict__ cB,
                          float* __restrict__ out) {
  int i = blockIdx.x * blockDim.x + threadIdx.x;  // b*OO + o
  float y = 0.0f;
  #pragma unroll 8
  for (int c = 0; c < NCH; c++) {
    float A  = cA[(size_t)c * (BB * OO) + i];
    float Bv = cB[(size_t)c * (BB * OO) + i];
    y = fmaf(A, y, Bv);
  }
  out[i] = y;
}

extern "C" void kernel_launch(void* const* d_in, const int* in_sizes, int n_in,
                              void* d_out, int out_size, void* d_ws, size_t ws_size,
                              hipStream_t stream) {
  (void)in_sizes; (void)n_in; (void)out_size; (void)ws_size;
  const float* x  = (const float*)d_in[0];
  const float* g  = (const float*)d_in[1];
  const float* gb = (const float*)d_in[2];
  const float* h  = (const float*)d_in[3];
  const float* hb = (const float*)d_in[4];
  const float* r  = (const float*)d_in[5];
  const float* rb = (const float*)d_in[6];
  float* out = (float*)d_out;

  char* w = (char*)d_ws;
  unsigned short* Gt = (unsigned short*)w;                       // 524288 B
  unsigned short* Ht = (unsigned short*)(w + 524288);            // 524288 B
  float* chunkA = (float*)(w + 1048576);                         // 8388608 B
  float* chunkB = (float*)(w + 9437184);                         // 8388608 B
  // total: 17825792 B

  static bool attr_set = false;
  if (!attr_set) {
    hipFuncSetAttribute(reinterpret_cast<const void*>(rnn_fused3_k),
                        hipFuncAttributeMaxDynamicSharedMemorySize, 131072);
    attr_set = true;
  }

  prep_weights_k<<<dim3(16, 16, 2), dim3(32, 8), 0, stream>>>(g, h, Gt, Ht);
  rnn_fused3_k<<<NCH * 4, 512, 131072, stream>>>(x, Gt, Ht, gb, hb, r, rb,
                                                 chunkA, chunkB);
  combine_k<<<(BB * OO) / 256, 256, 0, stream>>>(chunkA, chunkB, out);
}

// Round 2
// 541.877 us; speedup vs baseline: 1.0793x; 1.0793x over previous
//
#include <hip/hip_runtime.h>
#include <cstdint>
#include <cstddef>

// Problem constants
#define TT   2048
#define BB   64
#define KK   512
#define OO   512
#define NCH  64      // time chunks
#define TC   32      // t-steps per chunk

typedef __attribute__((ext_vector_type(8))) short short8;
typedef __attribute__((ext_vector_type(4))) float f32x4;

__device__ __forceinline__ unsigned short f2bf(float f) {
  unsigned int u = __float_as_uint(f);
  unsigned int rounding = 0x7FFFu + ((u >> 16) & 1u);
  return (unsigned short)((u + rounding) >> 16);
}

__device__ __forceinline__ float sigmoid_f(float z) {
  return 1.0f / (1.0f + __expf(-z));
}

__device__ __forceinline__ float tanh_f(float z) {
  z = fminf(15.0f, fmaxf(-15.0f, z));
  float e = __expf(-2.0f * z);
  return (1.0f - e) / (1.0f + e);
}

__device__ __forceinline__ void async_ld16(const void* g, void* l) {
  __builtin_amdgcn_global_load_lds(
      (const __attribute__((address_space(1))) void*)g,
      (__attribute__((address_space(3))) void*)l, 16, 0, 0);
}

// ---------------- kernel 1: x fp32 -> bf16 ----------------
__global__ void convert_x_k(const float4* __restrict__ x4,
                            ushort4* __restrict__ xb4, int n4) {
  int i = blockIdx.x * blockDim.x + threadIdx.x;
  int stride = gridDim.x * blockDim.x;
  for (; i < n4; i += stride) {
    float4 v = x4[i];
    ushort4 o;
    o.x = f2bf(v.x); o.y = f2bf(v.y); o.z = f2bf(v.z); o.w = f2bf(v.w);
    xb4[i] = o;
  }
}

// ---------------- kernel 2: transpose+convert weights ----------------
// Gt[o][k] = bf16(g[k][o]); Ht likewise. grid (16,16,2), block (32,8)
__global__ void prep_weights_k(const float* __restrict__ g,
                               const float* __restrict__ h,
                               unsigned short* __restrict__ Gt,
                               unsigned short* __restrict__ Ht) {
  __shared__ float tile[32][33];
  const float* src = (blockIdx.z == 0) ? g : h;
  unsigned short* dst = (blockIdx.z == 0) ? Gt : Ht;
  int ox = blockIdx.x * 32;   // o base
  int ky = blockIdx.y * 32;   // k base
  int tx = threadIdx.x, ty = threadIdx.y;
  #pragma unroll
  for (int r = ty; r < 32; r += 8)
    tile[r][tx] = src[(ky + r) * OO + ox + tx];
  __syncthreads();
  #pragma unroll
  for (int r = ty; r < 32; r += 8)
    dst[(size_t)(ox + r) * KK + ky + tx] = f2bf(tile[tx][r]);
}

// ---------------- kernel 3: register-B fused GEMM + gates + scan ----------
// 256 blocks (1/CU), 512 threads (8 waves = 2/SIMD). Weights in VGPRs:
// wave w owns o-cols [ot*128 + 16w, +16) of BOTH G and H (128 VGPRs).
//
// T3+T4+T5 phase pipeline (the round-0 structural fix): each t-step is 2
// half-K phases over a 4-buffer ring (4 x 32 KB half-tiles, 64 rows x 256 k
// bf16). Prefetch depth = 3 half-tiles (12 DMA loads/wave in flight). Raw
// s_barrier + counted `s_waitcnt vmcnt(8)` -- NEVER vmcnt(0) in the loop --
// so the 2 newer stages stay in flight ACROSS the barrier. (__syncthreads
// would emit vmcnt(0) and re-create round-0's per-iteration DMA-tail drain.)
// stage(s+3) is issued AFTER the barrier: the barrier proves all waves
// finished reading buffer (s-1)&3 == (s+3)&3, so the overwrite is safe.
// Each wave waits only its OWN 4 loads of stage s (FIFO) pre-barrier; the
// barrier then proves all waves' stage-s DMA landed.
__global__ __launch_bounds__(512, 2) void rnn_fused4_k(
    const unsigned short* __restrict__ xb,   // [T*B][K] bf16
    const unsigned short* __restrict__ Gt,   // [OO][KK] bf16
    const unsigned short* __restrict__ Ht,   // [OO][KK] bf16
    const float* __restrict__ gb, const float* __restrict__ hb,
    const float* __restrict__ r,  const float* __restrict__ rb,
    float* __restrict__ chunkA, float* __restrict__ chunkB) {
  extern __shared__ __align__(16) unsigned short smem[];  // 4 x [64][256]

  const int tid  = threadIdx.x;
  const int wave = tid >> 6;   // 0..7
  const int lane = tid & 63;
  const int quad = lane >> 4;
  const int lcol = lane & 15;

  // bi = ot*64 + c: the 4 o-tiles of chunk c share bi%8 -> same XCD (L2 reuse)
  const int bi = blockIdx.x;
  const int ot = bi >> 6;      // 0..3
  const int c  = bi & 63;      // 0..63
  const int o  = ot * 128 + wave * 16 + lcol;   // this thread's output column

  const float gbv = gb[o], hbv = hb[o];
  const float rv  = r[o],  rbv = rb[o];

  // ---- weights into registers: 16 cols x K512 x {G,H} = 128 VGPRs ----
  // Bg[K16] covers k in [K16*32 + quad*8, +8) for this thread's o-column.
  short8 Bg[16], Bh[16];
  {
    const unsigned short* gp = Gt + (size_t)o * KK + quad * 8;
    const unsigned short* hp = Ht + (size_t)o * KK + quad * 8;
    #pragma unroll
    for (int K16 = 0; K16 < 16; ++K16) {
      Bg[K16] = *(const short8*)(gp + K16 * 32);
      Bh[K16] = *(const short8*)(hp + K16 * 32);
    }
  }

  // stage half-tile s (t = c*TC + s/2, k-half = s&1) into ring buffer s&3.
  // One DMA instr covers 2 rows (64 lanes x 16B = 1024 B = 2 x 512 B rows).
  // LDS slot (lane&31) of row r holds global 16B-chunk (lane&31)^(r&7)
  // (involution; read side applies the same XOR -> bank-spread reads).
  auto stage = [&](int s) {
    unsigned short* dst = smem + (s & 3) * 16384 + wave * 2048;
    const int t = c * TC + (s >> 1);
    const unsigned short* srcb = xb + (size_t)t * (BB * KK) + (s & 1) * 256;
    #pragma unroll
    for (int j = 0; j < 4; ++j) {
      int rr  = 2 * j + (lane >> 5);          // row within wave slab (== r&7)
      int gch = (lane & 31) ^ rr;             // swizzled global 16B chunk
      async_ld16(srcb + (size_t)(wave * 8 + rr) * KK + gch * 8,
                 dst + j * 512);
    }
  };

  // prologue: 3 half-tiles in flight
  stage(0); stage(1); stage(2);

  // chunk-scan state per (b,o) slot: y_out = SB + SA*y_in
  float SA[16], SB[16];
  #pragma unroll
  for (int s2 = 0; s2 < 16; ++s2) { SA[s2] = 1.0f; SB[s2] = 0.0f; }

  f32x4 accG[4], accH[4];
  #pragma unroll
  for (int m = 0; m < 4; m++) {
    f32x4 z = {0.0f, 0.0f, 0.0f, 0.0f};
    accG[m] = z; accH[m] = z;
  }

  for (int t = 0; t < TC; ++t) {
    const int b0 = (t & 1) * 2;              // (2t)&3
    #pragma unroll
    for (int h = 0; h < 2; ++h) {
      // counted wait: stage s=2t+h landed; stages s+1, s+2 (8 loads) stay
      // in flight across the barrier. Tail: t=31 has 8 then 4 outstanding.
      if (t < TC - 1) {
        asm volatile("s_waitcnt vmcnt(8)" ::: "memory");
      } else if (h == 0) {
        asm volatile("s_waitcnt vmcnt(4)" ::: "memory");
      } else {
        asm volatile("s_waitcnt vmcnt(0)" ::: "memory");
      }
      __builtin_amdgcn_sched_barrier(0);
      __builtin_amdgcn_s_barrier();

      const int sn = 2 * t + h + 3;
      if (sn < 2 * TC) stage(sn);            // refill ring 3 phases ahead

      const unsigned short* A0 = smem + (b0 + h) * 16384;
      __builtin_amdgcn_s_setprio(1);
      #pragma unroll
      for (int k2 = 0; k2 < 8; ++k2) {
        const int K16 = h * 8 + k2;
        #pragma unroll
        for (int mt = 0; mt < 4; ++mt) {
          const int arow = mt * 16 + lcol;
          const int sl   = (k2 * 4 + quad) ^ (lcol & 7);
          short8 a = *(const short8*)(A0 + arow * 256 + sl * 8);
          accG[mt] = __builtin_amdgcn_mfma_f32_16x16x32_bf16(
              a, Bg[K16], accG[mt], 0, 0, 0);
          accH[mt] = __builtin_amdgcn_mfma_f32_16x16x32_bf16(
              a, Bh[K16], accH[mt], 0, 0, 0);
        }
      }
      __builtin_amdgcn_s_setprio(0);
    }

    // epilogue: one t-step of the recurrence, folded into (SA,SB)
    const int tt = c * TC + t;
    const float rt = 2.0f * sigmoid_f(((float)tt * (1.0f / TT)) * rv + rbv);
    #pragma unroll
    for (int mt = 0; mt < 4; ++mt)
      #pragma unroll
      for (int reg = 0; reg < 4; ++reg) {
        float G = sigmoid_f(accG[mt][reg] + gbv) * rt;
        float H = tanh_f  (accH[mt][reg] + hbv) * rt;
        int s2 = mt * 4 + reg;
        SB[s2] = fmaf(G, SB[s2], H);
        SA[s2] *= G;
        accG[mt][reg] = 0.0f;
        accH[mt][reg] = 0.0f;
      }
  }

  // write chunk composition: layout [c][b][o]
  #pragma unroll
  for (int mt = 0; mt < 4; ++mt)
    #pragma unroll
    for (int reg = 0; reg < 4; ++reg) {
      int s2 = mt * 4 + reg;
      int b = mt * 16 + quad * 4 + reg;
      size_t idx = ((size_t)c * BB + b) * OO + o;
      chunkA[idx] = SA[s2];
      chunkB[idx] = SB[s2];
    }
}

// ---------------- kernel 4: fold chunks ----------------
__global__ void combine_k(const float* __restrict__ cA,
                          const float* __restrict__ cB,
                          float* __restrict__ out) {
  int i = blockIdx.x * blockDim.x + threadIdx.x;  // b*OO + o
  float y = 0.0f;
  #pragma unroll 8
  for (int c = 0; c < NCH; c++) {
    float A  = cA[(size_t)c * (BB * OO) + i];
    float Bv = cB[(size_t)c * (BB * OO) + i];
    y = fmaf(A, y, Bv);
  }
  out[i] = y;
}

extern "C" void kernel_launch(void* const* d_in, const int* in_sizes, int n_in,
                              void* d_out, int out_size, void* d_ws, size_t ws_size,
                              hipStream_t stream) {
  (void)in_sizes; (void)n_in; (void)out_size; (void)ws_size;
  const float* x  = (const float*)d_in[0];
  const float* g  = (const float*)d_in[1];
  const float* gb = (const float*)d_in[2];
  const float* h  = (const float*)d_in[3];
  const float* hb = (const float*)d_in[4];
  const float* r  = (const float*)d_in[5];
  const float* rb = (const float*)d_in[6];
  float* out = (float*)d_out;

  char* w = (char*)d_ws;
  unsigned short* xb = (unsigned short*)w;                       // 134217728 B
  unsigned short* Gt = (unsigned short*)(w + 134217728);         // 524288 B
  unsigned short* Ht = (unsigned short*)(w + 134742016);         // 524288 B
  float* chunkA = (float*)(w + 135266304);                       // 8388608 B
  float* chunkB = (float*)(w + 143654912);                       // 8388608 B
  // total: 152043520 B

  static bool attr_set = false;
  if (!attr_set) {
    hipFuncSetAttribute(reinterpret_cast<const void*>(rnn_fused4_k),
                        hipFuncAttributeMaxDynamicSharedMemorySize, 131072);
    attr_set = true;
  }

  const int n4 = (TT * BB * KK) / 4;  // 16777216 float4s
  convert_x_k<<<8192, 256, 0, stream>>>((const float4*)x, (ushort4*)xb, n4);
  prep_weights_k<<<dim3(16, 16, 2), dim3(32, 8), 0, stream>>>(g, h, Gt, Ht);
  rnn_fused4_k<<<NCH * 4, 512, 131072, stream>>>(xb, Gt, Ht, gb, hb, r, rb,
                                                 chunkA, chunkB);
  combine_k<<<(BB * OO) / 256, 256, 0, stream>>>(chunkA, chunkB, out);
}